// Round 6
// baseline (153.166 us; speedup 1.0000x reference)
//
#include <hip/hip_runtime.h>

#define FEPS 1e-8f
#define NSLOTS 64           // cache-line-spread partial slots
#define SLOT_STRIDE 64      // bytes

// Liang-Barsky clip of segment p + t*d, t in [0,1], against rectangle
// {center c, unit axis (ux,uy), half-sizes hw,hh}; accumulates shoelace
// contribution cross(P(t0), P(t1)) of the surviving sub-segment.
// Boundary of P∩Q = (edges of P in Q) ∪ (edges of Q in P) in CCW order;
// the shoelace sum over directed pieces is ordering-invariant.
__device__ __forceinline__ void clip_edge_accum(
    float px, float py, float dx, float dy,
    float cx, float cy, float ux, float uy,
    float hw, float hh, float& sum)
{
    float rx = px - cx, ry = py - cy;
    float a0 = rx * ux + ry * uy;
    float b0 = dx * ux + dy * uy;
    float a1 = -rx * uy + ry * ux;
    float b1 = -dx * uy + dy * ux;

    float t0 = 0.0f, t1 = 1.0f;
    bool reject = false;
    {
        bool par = fabsf(b0) < 1e-12f;
        float inv = 1.0f / (par ? 1.0f : b0);
        float tA = (hw - a0) * inv, tB = (-hw - a0) * inv;
        t0 = par ? t0 : fmaxf(t0, fminf(tA, tB));
        t1 = par ? t1 : fminf(t1, fmaxf(tA, tB));
        reject = reject || (par && (fabsf(a0) > hw));
    }
    {
        bool par = fabsf(b1) < 1e-12f;
        float inv = 1.0f / (par ? 1.0f : b1);
        float tA = (hh - a1) * inv, tB = (-hh - a1) * inv;
        t0 = par ? t0 : fmaxf(t0, fminf(tA, tB));
        t1 = par ? t1 : fminf(t1, fmaxf(tA, tB));
        reject = reject || (par && (fabsf(a1) > hh));
    }
    bool ok = (!reject) && (t1 > t0);
    float sx = px + t0 * dx, sy = py + t0 * dy;
    float ex = px + t1 * dx, ey = py + t1 * dy;
    sum += ok ? (sx * ey - ex * sy) : 0.0f;
}

__device__ __forceinline__ float one_iou(
    float p0, float p1, float p2, float p3, float p4,
    float t0, float t1, float t2, float t3, float t4)
{
    const float DEG = 0.017453292519943295f;
    float a1 = p4 * DEG;                       // deg2rad(pred angle)
    float a2 = (t4 * 180.0f - 180.0f) * DEG;   // deg2rad(target*180-180)
    float s1 = __sinf(a1), c1_ = __cosf(a1);
    float s2 = __sinf(a2), c2_ = __cosf(a2);

    float hw1 = 0.5f * p2, hh1 = 0.5f * p3;
    float hw2 = 0.5f * t2, hh2 = 0.5f * t3;

    const float SX[4] = {0.5f, -0.5f, -0.5f, 0.5f};
    const float SY[4] = {0.5f, 0.5f, -0.5f, -0.5f};
    float P1x[4], P1y[4], P2x[4], P2y[4];
    #pragma unroll
    for (int k = 0; k < 4; ++k) {
        float xs = SX[k] * p2, ys = SY[k] * p3;
        P1x[k] = xs * c1_ - ys * s1 + p0;
        P1y[k] = xs * s1 + ys * c1_ + p1;
        float xs2 = SX[k] * t2, ys2 = SY[k] * t3;
        P2x[k] = xs2 * c2_ - ys2 * s2 + t0;
        P2y[k] = xs2 * s2 + ys2 * c2_ + t1;
    }

    float sum = 0.0f;
    #pragma unroll
    for (int k = 0; k < 4; ++k) {
        int kn = (k + 1) & 3;
        clip_edge_accum(P1x[k], P1y[k], P1x[kn]-P1x[k], P1y[kn]-P1y[k],
                        t0, t1, c2_, s2, hw2, hh2, sum);
    }
    #pragma unroll
    for (int k = 0; k < 4; ++k) {
        int kn = (k + 1) & 3;
        clip_edge_accum(P2x[k], P2y[k], P2x[kn]-P2x[k], P2y[kn]-P2y[k],
                        p0, p1, c1_, s1, hw1, hh1, sum);
    }

    float inter = 0.5f * fabsf(sum);
    float uni = p2 * p3 + t2 * t3 - inter;
    float iou = inter / (uni + FEPS);
    return fminf(fmaxf(iou, 1e-7f), 1.0f - 1e-7f);
}

// ws layout: NSLOTS slots of 64B {float num; float den}, then unsigned ticket
// at ws+NSLOTS*64. Fully fused: last block reduces the slots in-kernel.
__global__ __launch_bounds__(256, 4) void riou_fused(
    const float* __restrict__ pred, const float* __restrict__ target,
    const int* __restrict__ pos_idx, float* __restrict__ out,
    char* __restrict__ ws, int n, int nblocks)
{
    int gid = blockIdx.x * blockDim.x + threadIdx.x;
    float lnum = 0.0f, lden = 0.0f;

    if (gid < n) {
        const float* p = pred + (size_t)gid * 5;
        const float* t = target + (size_t)gid * 5;
        float iou = one_iou(p[0], p[1], p[2], p[3], p[4],
                            t[0], t[1], t[2], t[3], t[4]);
        out[1 + gid] = iou;
        float m = (pos_idx[gid] != 0) ? 1.0f : 0.0f;
        lnum = (1.0f - iou) * m;
        lden = m;
    }

    // block reduction (wave shuffle + cross-wave LDS)
    #pragma unroll
    for (int off = 32; off > 0; off >>= 1) {
        lnum += __shfl_down(lnum, off);
        lden += __shfl_down(lden, off);
    }
    __shared__ float snum[4], sden[4];
    __shared__ int slast;
    int wave = threadIdx.x >> 6, lane = threadIdx.x & 63;
    if (lane == 0) { snum[wave] = lnum; sden[wave] = lden; }
    __syncthreads();

    if (threadIdx.x == 0) {
        float bn = snum[0] + snum[1] + snum[2] + snum[3];
        float bd = sden[0] + sden[1] + sden[2] + sden[3];
        char* slot = ws + (size_t)(blockIdx.x & (NSLOTS - 1)) * SLOT_STRIDE;
        atomicAdd((float*)slot, bn);
        atomicAdd((float*)(slot + 4), bd);
        __threadfence();
        unsigned t = atomicAdd((unsigned*)(ws + NSLOTS * SLOT_STRIDE), 1u);
        slast = (t == (unsigned)(nblocks - 1)) ? 1 : 0;
    }
    __syncthreads();

    if (slast) {   // last arriving block finalizes the loss
        float num = 0.0f, den = 0.0f;
        if (threadIdx.x < NSLOTS) {
            char* slot = ws + (size_t)threadIdx.x * SLOT_STRIDE;
            // atomic fetch = device-coherent read (plain load may hit stale L1/L2)
            num = atomicAdd((float*)slot, 0.0f);
            den = atomicAdd((float*)(slot + 4), 0.0f);
        }
        if (threadIdx.x < 64) {
            #pragma unroll
            for (int off = 32; off > 0; off >>= 1) {
                num += __shfl_down(num, off);
                den += __shfl_down(den, off);
            }
            if (threadIdx.x == 0)
                out[0] = num / fmaxf(den, 1.0f);
        }
    }
}

extern "C" void kernel_launch(void* const* d_in, const int* in_sizes, int n_in,
                              void* d_out, int out_size, void* d_ws, size_t ws_size,
                              hipStream_t stream) {
    const float* pred   = (const float*)d_in[0];
    const float* target = (const float*)d_in[1];
    const int*   posidx = (const int*)d_in[2];
    float* out = (float*)d_out;

    int n = in_sizes[0] / 5;
    int block = 256;
    int grid = (n + block - 1) / block;

    // zero the 64 partial slots + ticket (d_ws is re-poisoned to 0xAA)
    hipMemsetAsync(d_ws, 0, NSLOTS * SLOT_STRIDE + 64, stream);

    riou_fused<<<grid, block, 0, stream>>>(pred, target, posidx, out,
                                           (char*)d_ws, n, grid);
}

// Round 7
// 88.540 us; speedup vs baseline: 1.7299x; 1.7299x over previous
//
#include <hip/hip_runtime.h>

#define FEPS 1e-8f

// v_rcp_f32: 1-instruction ~1ulp reciprocal (vs ~12-instr IEEE div sequence).
// Safe here: every use is guarded so the denominator is never subnormal.
__device__ __forceinline__ float fastrcp(float x) {
    return __builtin_amdgcn_rcpf(x);
}

// Liang-Barsky clip of segment p + t*d, t in [0,1], against rectangle
// {center c, unit axis (ux,uy), half-sizes hw,hh}; accumulates shoelace
// contribution cross(P(t0), P(t1)) of the surviving sub-segment.
// Boundary of P∩Q = (edges of P in Q) ∪ (edges of Q in P) in CCW order;
// the shoelace sum over directed pieces is ordering-invariant.
__device__ __forceinline__ void clip_edge_accum(
    float px, float py, float dx, float dy,
    float cx, float cy, float ux, float uy,
    float hw, float hh, float& sum)
{
    float rx = px - cx, ry = py - cy;
    float a0 = rx * ux + ry * uy;
    float b0 = dx * ux + dy * uy;
    float a1 = -rx * uy + ry * ux;
    float b1 = -dx * uy + dy * ux;

    float t0 = 0.0f, t1 = 1.0f;
    bool reject = false;
    {
        bool par = fabsf(b0) < 1e-12f;
        float inv = fastrcp(par ? 1.0f : b0);
        float tA = (hw - a0) * inv, tB = (-hw - a0) * inv;
        t0 = par ? t0 : fmaxf(t0, fminf(tA, tB));
        t1 = par ? t1 : fminf(t1, fmaxf(tA, tB));
        reject = reject || (par && (fabsf(a0) > hw));
    }
    {
        bool par = fabsf(b1) < 1e-12f;
        float inv = fastrcp(par ? 1.0f : b1);
        float tA = (hh - a1) * inv, tB = (-hh - a1) * inv;
        t0 = par ? t0 : fmaxf(t0, fminf(tA, tB));
        t1 = par ? t1 : fminf(t1, fmaxf(tA, tB));
        reject = reject || (par && (fabsf(a1) > hh));
    }
    bool ok = (!reject) && (t1 > t0);
    float sx = px + t0 * dx, sy = py + t0 * dy;
    float ex = px + t1 * dx, ey = py + t1 * dy;
    sum += ok ? (sx * ey - ex * sy) : 0.0f;
}

__device__ __forceinline__ float one_iou(
    float p0, float p1, float p2, float p3, float p4,
    float t0, float t1, float t2, float t3, float t4)
{
    const float DEG = 0.017453292519943295f;
    float a1 = p4 * DEG;                       // deg2rad(pred angle)
    float a2 = (t4 * 180.0f - 180.0f) * DEG;   // deg2rad(target*180-180)
    float s1 = __sinf(a1), c1_ = __cosf(a1);
    float s2 = __sinf(a2), c2_ = __cosf(a2);

    float hw1 = 0.5f * p2, hh1 = 0.5f * p3;
    float hw2 = 0.5f * t2, hh2 = 0.5f * t3;

    const float SX[4] = {0.5f, -0.5f, -0.5f, 0.5f};
    const float SY[4] = {0.5f, 0.5f, -0.5f, -0.5f};
    float P1x[4], P1y[4], P2x[4], P2y[4];
    #pragma unroll
    for (int k = 0; k < 4; ++k) {
        float xs = SX[k] * p2, ys = SY[k] * p3;
        P1x[k] = xs * c1_ - ys * s1 + p0;
        P1y[k] = xs * s1 + ys * c1_ + p1;
        float xs2 = SX[k] * t2, ys2 = SY[k] * t3;
        P2x[k] = xs2 * c2_ - ys2 * s2 + t0;
        P2y[k] = xs2 * s2 + ys2 * c2_ + t1;
    }

    float sum = 0.0f;
    #pragma unroll
    for (int k = 0; k < 4; ++k) {
        int kn = (k + 1) & 3;
        clip_edge_accum(P1x[k], P1y[k], P1x[kn]-P1x[k], P1y[kn]-P1y[k],
                        t0, t1, c2_, s2, hw2, hh2, sum);
    }
    #pragma unroll
    for (int k = 0; k < 4; ++k) {
        int kn = (k + 1) & 3;
        clip_edge_accum(P2x[k], P2y[k], P2x[kn]-P2x[k], P2y[kn]-P2y[k],
                        p0, p1, c1_, s1, hw1, hh1, sum);
    }

    float inter = 0.5f * fabsf(sum);
    float uni = p2 * p3 + t2 * t3 - inter;
    float iou = inter * fastrcp(uni + FEPS);   // uni >= max(area)/2 > 0 here
    return fminf(fmaxf(iou, 1e-7f), 1.0f - 1e-7f);
}

// One box per thread; per-block partial STORED (not atomic) to its own slot.
// Every slot is written every launch -> no workspace init, no memset, and
// crucially NO same-line atomic chain (round 6 showed a single ticket line
// costs ~90us at 3072 blocks).
__global__ __launch_bounds__(256) void riou_kernel(
    const float* __restrict__ pred, const float* __restrict__ target,
    const int* __restrict__ pos_idx, float* __restrict__ out,
    float2* __restrict__ partials, int n)
{
    int gid = blockIdx.x * blockDim.x + threadIdx.x;
    float lnum = 0.0f, lden = 0.0f;

    if (gid < n) {
        const float* p = pred + (size_t)gid * 5;
        const float* t = target + (size_t)gid * 5;
        float iou = one_iou(p[0], p[1], p[2], p[3], p[4],
                            t[0], t[1], t[2], t[3], t[4]);
        out[1 + gid] = iou;
        float m = (pos_idx[gid] != 0) ? 1.0f : 0.0f;
        lnum = (1.0f - iou) * m;
        lden = m;
    }

    #pragma unroll
    for (int off = 32; off > 0; off >>= 1) {
        lnum += __shfl_down(lnum, off);
        lden += __shfl_down(lden, off);
    }
    __shared__ float snum[4], sden[4];
    int wave = threadIdx.x >> 6, lane = threadIdx.x & 63;
    if (lane == 0) { snum[wave] = lnum; sden[wave] = lden; }
    __syncthreads();
    if (threadIdx.x == 0) {
        float bn = snum[0] + snum[1] + snum[2] + snum[3];
        float bd = sden[0] + sden[1] + sden[2] + sden[3];
        partials[blockIdx.x] = make_float2(bn, bd);
    }
}

__global__ __launch_bounds__(1024) void riou_finalize(
    const float2* __restrict__ partials, int nb, float* __restrict__ out)
{
    double num = 0.0, den = 0.0;
    for (int i = threadIdx.x; i < nb; i += 1024) {   // 3 iters at nb=3072
        float2 p = partials[i];
        num += (double)p.x;
        den += (double)p.y;
    }
    #pragma unroll
    for (int off = 32; off > 0; off >>= 1) {
        num += __shfl_down(num, off);
        den += __shfl_down(den, off);
    }
    __shared__ double dn[16], dd[16];
    int wave = threadIdx.x >> 6, lane = threadIdx.x & 63;
    if (lane == 0) { dn[wave] = num; dd[wave] = den; }
    __syncthreads();
    if (threadIdx.x == 0) {
        double n2 = 0.0, d2 = 0.0;
        #pragma unroll
        for (int w = 0; w < 16; ++w) { n2 += dn[w]; d2 += dd[w]; }
        out[0] = (float)(n2 / fmax(d2, 1.0));
    }
}

extern "C" void kernel_launch(void* const* d_in, const int* in_sizes, int n_in,
                              void* d_out, int out_size, void* d_ws, size_t ws_size,
                              hipStream_t stream) {
    const float* pred   = (const float*)d_in[0];
    const float* target = (const float*)d_in[1];
    const int*   posidx = (const int*)d_in[2];
    float* out = (float*)d_out;

    int n = in_sizes[0] / 5;
    int block = 256;
    int grid = (n + block - 1) / block;
    float2* partials = (float2*)d_ws;

    riou_kernel<<<grid, block, 0, stream>>>(pred, target, posidx, out,
                                            partials, n);
    riou_finalize<<<1, 1024, 0, stream>>>(partials, grid, out);
}

// Round 8
// 86.810 us; speedup vs baseline: 1.7644x; 1.0199x over previous
//
#include <hip/hip_runtime.h>

#define FEPS 1e-8f

// v_rcp_f32: 1-instruction ~1ulp reciprocal. rcp(±0)=±inf gives correct
// Liang-Barsky behavior for axis-parallel edges (slab -> no constraint or
// reject via t1<t0), so no parallel-edge guard is needed.
__device__ __forceinline__ float fastrcp(float x) {
    return __builtin_amdgcn_rcpf(x);
}

// Clip one edge (frame coords a,b = start,direction in the clipping box's
// axis frame; world coords Pw,Dw) against slabs [-hw,hw]x[-hh,hh], and
// accumulate the shoelace contribution cross(s,e) of the surviving piece
// with s,e evaluated in WORLD frame (t is frame-invariant).
__device__ __forceinline__ void clip_edge_accum(
    float a0, float a1, float b0, float b1,
    float pwx, float pwy, float dwx, float dwy,
    float hw, float hh, float& sum)
{
    float inv0 = fastrcp(b0);
    float tA0 = (hw - a0) * inv0, tB0 = (-hw - a0) * inv0;
    float inv1 = fastrcp(b1);
    float tA1 = (hh - a1) * inv1, tB1 = (-hh - a1) * inv1;

    float lo0 = fminf(tA0, tB0), hi0 = fmaxf(tA0, tB0);
    float lo1 = fminf(tA1, tB1), hi1 = fmaxf(tA1, tB1);

    float t0 = fmaxf(0.0f, fmaxf(lo0, lo1));   // v_max3
    float t1 = fminf(1.0f, fminf(hi0, hi1));   // v_min3

    bool ok = t1 > t0;
    float sx = pwx + t0 * dwx, sy = pwy + t0 * dwy;
    float ex = pwx + t1 * dwx, ey = pwy + t1 * dwy;
    sum += ok ? (sx * ey - ex * sy) : 0.0f;
}

__device__ __forceinline__ float one_iou(
    float p0, float p1, float p2, float p3, float p4,
    float t0, float t1, float t2, float t3, float t4)
{
    const float DEG = 0.017453292519943295f;
    float a1 = p4 * DEG;                       // deg2rad(pred angle)
    float a2 = (t4 * 180.0f - 180.0f) * DEG;   // deg2rad(target*180-180)
    float s1 = __sinf(a1), c1 = __cosf(a1);
    float s2 = __sinf(a2), c2 = __cosf(a2);

    float hw1 = 0.5f * p2, hh1 = 0.5f * p3;
    float hw2 = 0.5f * t2, hh2 = 0.5f * t3;

    const float SX[4] = {0.5f, -0.5f, -0.5f, 0.5f};
    const float SY[4] = {0.5f, 0.5f, -0.5f, -0.5f};

    // world-frame corners
    float P1x[4], P1y[4], P2x[4], P2y[4];
    // corners of box1 in box2's frame, and vice versa
    float F1x[4], F1y[4], F2x[4], F2y[4];
    #pragma unroll
    for (int k = 0; k < 4; ++k) {
        float xs = SX[k] * p2, ys = SY[k] * p3;
        P1x[k] = xs * c1 - ys * s1 + p0;
        P1y[k] = xs * s1 + ys * c1 + p1;
        float xs2 = SX[k] * t2, ys2 = SY[k] * t3;
        P2x[k] = xs2 * c2 - ys2 * s2 + t0;
        P2y[k] = xs2 * s2 + ys2 * c2 + t1;
    }
    #pragma unroll
    for (int k = 0; k < 4; ++k) {
        float dx = P1x[k] - t0, dy = P1y[k] - t1;
        F1x[k] =  dx * c2 + dy * s2;           // u-axis of box2
        F1y[k] = -dx * s2 + dy * c2;           // v-axis of box2
        float ex = P2x[k] - p0, ey = P2y[k] - p1;
        F2x[k] =  ex * c1 + ey * s1;           // u-axis of box1
        F2y[k] = -ex * s1 + ey * c1;           // v-axis of box1
    }

    float sum = 0.0f;
    #pragma unroll
    for (int k = 0; k < 4; ++k) {
        int kn = (k + 1) & 3;
        clip_edge_accum(F1x[k], F1y[k], F1x[kn]-F1x[k], F1y[kn]-F1y[k],
                        P1x[k], P1y[k], P1x[kn]-P1x[k], P1y[kn]-P1y[k],
                        hw2, hh2, sum);
    }
    #pragma unroll
    for (int k = 0; k < 4; ++k) {
        int kn = (k + 1) & 3;
        clip_edge_accum(F2x[k], F2y[k], F2x[kn]-F2x[k], F2y[kn]-F2y[k],
                        P2x[k], P2y[k], P2x[kn]-P2x[k], P2y[kn]-P2y[k],
                        hw1, hh1, sum);
    }

    float inter = 0.5f * fabsf(sum);
    float uni = p2 * p3 + t2 * t3 - inter;
    float iou = inter * fastrcp(uni + FEPS);
    return fminf(fmaxf(iou, 1e-7f), 1.0f - 1e-7f);
}

// One box per thread; per-block partial STORED (not atomic) to its own slot.
// Every slot written every launch -> no init, no memset, and no same-line
// atomic chain (round 6: a single ticket line costs ~90us at 3072 blocks).
__global__ __launch_bounds__(256) void riou_kernel(
    const float* __restrict__ pred, const float* __restrict__ target,
    const int* __restrict__ pos_idx, float* __restrict__ out,
    float2* __restrict__ partials, int n)
{
    int gid = blockIdx.x * blockDim.x + threadIdx.x;
    float lnum = 0.0f, lden = 0.0f;

    if (gid < n) {
        const float* p = pred + (size_t)gid * 5;
        const float* t = target + (size_t)gid * 5;
        float iou = one_iou(p[0], p[1], p[2], p[3], p[4],
                            t[0], t[1], t[2], t[3], t[4]);
        out[1 + gid] = iou;
        float m = (pos_idx[gid] != 0) ? 1.0f : 0.0f;
        lnum = (1.0f - iou) * m;
        lden = m;
    }

    #pragma unroll
    for (int off = 32; off > 0; off >>= 1) {
        lnum += __shfl_down(lnum, off);
        lden += __shfl_down(lden, off);
    }
    __shared__ float snum[4], sden[4];
    int wave = threadIdx.x >> 6, lane = threadIdx.x & 63;
    if (lane == 0) { snum[wave] = lnum; sden[wave] = lden; }
    __syncthreads();
    if (threadIdx.x == 0) {
        float bn = snum[0] + snum[1] + snum[2] + snum[3];
        float bd = sden[0] + sden[1] + sden[2] + sden[3];
        partials[blockIdx.x] = make_float2(bn, bd);
    }
}

__global__ __launch_bounds__(1024) void riou_finalize(
    const float2* __restrict__ partials, int nb, float* __restrict__ out)
{
    double num = 0.0, den = 0.0;
    for (int i = threadIdx.x; i < nb; i += 1024) {   // 3 iters at nb=3072
        float2 p = partials[i];
        num += (double)p.x;
        den += (double)p.y;
    }
    #pragma unroll
    for (int off = 32; off > 0; off >>= 1) {
        num += __shfl_down(num, off);
        den += __shfl_down(den, off);
    }
    __shared__ double dn[16], dd[16];
    int wave = threadIdx.x >> 6, lane = threadIdx.x & 63;
    if (lane == 0) { dn[wave] = num; dd[wave] = den; }
    __syncthreads();
    if (threadIdx.x == 0) {
        double n2 = 0.0, d2 = 0.0;
        #pragma unroll
        for (int w = 0; w < 16; ++w) { n2 += dn[w]; d2 += dd[w]; }
        out[0] = (float)(n2 / fmax(d2, 1.0));
    }
}

extern "C" void kernel_launch(void* const* d_in, const int* in_sizes, int n_in,
                              void* d_out, int out_size, void* d_ws, size_t ws_size,
                              hipStream_t stream) {
    const float* pred   = (const float*)d_in[0];
    const float* target = (const float*)d_in[1];
    const int*   posidx = (const int*)d_in[2];
    float* out = (float*)d_out;

    int n = in_sizes[0] / 5;
    int block = 256;
    int grid = (n + block - 1) / block;
    float2* partials = (float2*)d_ws;

    riou_kernel<<<grid, block, 0, stream>>>(pred, target, posidx, out,
                                            partials, n);
    riou_finalize<<<1, 1024, 0, stream>>>(partials, grid, out);
}